// Round 1
// baseline (154.696 us; speedup 1.0000x reference)
//
#include <hip/hip_runtime.h>
#include <math.h>

// Problem constants
#define L_SEQ 8192
#define B_N   8
#define D_MOD 512
#define H_N   8

// Workspace layout (float offsets)
#define QRAW_OFF 0                    // [1683]
#define QF_OFF   2048                 // [512]
#define QKV_OFF  2560                 // [8][512]  (h-major)
#define CK_OFF   6656                 // [8]
#define SC_OFF   8192                 // [B][L][H] = 524288
#define Y_OFF    (8192 + 524288)      // [B][H][512] = 32768
#define V_OFF    (Y_OFF + 32768)      // [B][512] = 4096
#define ROW_OFF  (V_OFF + 4096)       // [B][512] = 4096

// ---- init: zero y, V = bv, row = bo (re-run every call; ws is not re-poisoned) ----
__global__ void k0_init(float* ws, const float* bv, const float* bo) {
    int i = blockIdx.x * 256 + threadIdx.x;
    if (i < 32768)      ws[Y_OFF + i] = 0.f;
    else if (i < 36864) ws[V_OFF + (i - 32768)] = bv[(i - 32768) & 511];
    else if (i < 40960) ws[ROW_OFF + (i - 36864)] = bo[(i - 36864) & 511];
}

// ---- qraw[i] = poi[i,:]·wq1 + bq1 ----
__global__ void k1_qraw(const float* __restrict__ poi, const float* __restrict__ wq1,
                        const float* __restrict__ bq1, float* ws) {
    int i = blockIdx.x * 256 + threadIdx.x;
    if (i >= 1683) return;
    float a = bq1[0];
#pragma unroll
    for (int j = 0; j < 24; ++j) a += poi[i * 24 + j] * wq1[j];
    ws[QRAW_OFF + i] = a;
}

// ---- qf[o] = qraw·wq2[:,o] + bq2[o] ----
__global__ void k2_qf(const float* __restrict__ wq2, const float* __restrict__ bq2, float* ws) {
    __shared__ float red[256];
    int o = blockIdx.x, t = threadIdx.x;
    float a = 0.f;
    for (int i = t; i < 1683; i += 256) a += ws[QRAW_OFF + i] * wq2[i * 512 + o];
    red[t] = a; __syncthreads();
    for (int s = 128; s > 0; s >>= 1) { if (t < s) red[t] += red[t + s]; __syncthreads(); }
    if (t == 0) ws[QF_OFF + o] = red[0] + bq2[o];
}

// ---- qk_vec[h,c] = sum_e qf[h*64+e]*wk[c, h*64+e];  ck[h] = sum_e qf*bk ----
__global__ void k3_qkvec(const float* __restrict__ wk, const float* __restrict__ bk, float* ws) {
    int idx = blockIdx.x * 256 + threadIdx.x;      // idx = h*512 + c
    int h = idx >> 9, c = idx & 511;
    const float* qf = ws + QF_OFF;
    float a = 0.f;
#pragma unroll 8
    for (int e = 0; e < 64; ++e) a += qf[h * 64 + e] * wk[c * 512 + h * 64 + e];
    ws[QKV_OFF + idx] = a;
    if (idx < 8) {
        float b = 0.f;
        for (int e = 0; e < 64; ++e) b += qf[idx * 64 + e] * bk[idx * 64 + e];
        ws[CK_OFF + idx] = b;
    }
}

// ---- pass 1: scores[b,s,h] = 0.125*(x[b,s,:]·qk_vec[h,:] + ck[h]) ; one wave per row ----
__global__ __launch_bounds__(256) void k4_scores(const float* __restrict__ x, float* ws) {
    __shared__ float qk[4096];
    __shared__ float ckl[8];
    int t = threadIdx.x;
    for (int i = t; i < 4096; i += 256) qk[i] = ws[QKV_OFF + i];
    if (t < 8) ckl[t] = ws[CK_OFF + t];
    __syncthreads();
    int lane = t & 63;
    int wave = (blockIdx.x << 2) | (t >> 6);
    const float4* qk4 = (const float4*)qk;
    float* sc = ws + SC_OFF;
    for (int r = wave; r < B_N * L_SEQ; r += 4096) {
        const float4* xp = (const float4*)(x + (size_t)r * 512);
        float4 xa = xp[lane * 2], xb = xp[lane * 2 + 1];
        float res = 0.f;
#pragma unroll
        for (int h = 0; h < 8; ++h) {
            float4 qa = qk4[h * 128 + lane * 2], qb = qk4[h * 128 + lane * 2 + 1];
            float p = xa.x * qa.x + xa.y * qa.y + xa.z * qa.z + xa.w * qa.w
                    + xb.x * qb.x + xb.y * qb.y + xb.z * qb.z + xb.w * qb.w;
#pragma unroll
            for (int m = 32; m > 0; m >>= 1) p += __shfl_xor(p, m, 64);
            res = (lane == h) ? p : res;
        }
        if (lane < 8) sc[(size_t)r * 8 + lane] = 0.125f * (res + ckl[lane]);
    }
}

// ---- softmax over s for each (b,h); in-place on scores ----
__global__ void k5_softmax(float* ws) {
    __shared__ float red[256];
    int bh = blockIdx.x;
    int b = bh >> 3, h = bh & 7;
    float* sc = ws + SC_OFF + (size_t)b * (L_SEQ * 8) + h;
    int t = threadIdx.x;
    float m = -1e30f;
    for (int s = t; s < L_SEQ; s += 256) m = fmaxf(m, sc[(size_t)s * 8]);
    red[t] = m; __syncthreads();
    for (int q = 128; q > 0; q >>= 1) { if (t < q) red[t] = fmaxf(red[t], red[t + q]); __syncthreads(); }
    m = red[0]; __syncthreads();
    float sum = 0.f;
    for (int s = t; s < L_SEQ; s += 256) {
        float e = expf(sc[(size_t)s * 8] - m);
        sc[(size_t)s * 8] = e;
        sum += e;
    }
    red[t] = sum; __syncthreads();
    for (int q = 128; q > 0; q >>= 1) { if (t < q) red[t] += red[t + q]; __syncthreads(); }
    float inv = 1.f / red[0];
    for (int s = t; s < L_SEQ; s += 256) sc[(size_t)s * 8] *= inv;
}

// ---- pass 2: y[b,h,c] += sum_s A[b,s,h]*x[b,s,c]  (chunked, atomic accumulate) ----
__global__ __launch_bounds__(512) void k6_y(const float* __restrict__ x, float* ws) {
    __shared__ float a[512];            // A chunk: 64 s-rows x 8 heads, contiguous
    int b = blockIdx.x >> 7;
    int ch = blockIdx.x & 127;
    int s0 = ch * 64;
    int t = threadIdx.x;                // column c
    a[t] = ws[SC_OFF + (size_t)b * (L_SEQ * 8) + (size_t)s0 * 8 + t];
    __syncthreads();
    float acc[8] = {0.f, 0.f, 0.f, 0.f, 0.f, 0.f, 0.f, 0.f};
    const float* xb = x + ((size_t)b * L_SEQ + s0) * 512 + t;
    for (int sl = 0; sl < 64; ++sl) {
        float xv = xb[(size_t)sl * 512];
#pragma unroll
        for (int h = 0; h < 8; ++h) acc[h] += a[sl * 8 + h] * xv;
    }
    float* y = ws + Y_OFF + (size_t)(b * 8) * 512 + t;
#pragma unroll
    for (int h = 0; h < 8; ++h) atomicAdd(y + h * 512, acc[h]);
}

// ---- V[b,o] = y[b, o>>6, :]·wv[:,o] + bv[o]  (bv folded into init) ----
__global__ __launch_bounds__(512) void k7_v(const float* __restrict__ wv, float* ws) {
    int b = blockIdx.x >> 3;
    int cp = blockIdx.x & 7;
    int o = threadIdx.x;
    int h = o >> 6;
    const float* y = ws + Y_OFF + (size_t)(b * 8 + h) * 512 + cp * 64;
    const float* w = wv + (size_t)(cp * 64) * 512 + o;
    float acc = 0.f;
#pragma unroll 8
    for (int ci = 0; ci < 64; ++ci) acc += y[ci] * w[(size_t)ci * 512];
    atomicAdd(ws + V_OFF + b * 512 + o, acc);
}

// ---- row[b,j] = V[b,:]·wo[:,j] + bo[j]  (bo folded into init) ----
__global__ __launch_bounds__(512) void k8_row(const float* __restrict__ wo, float* ws) {
    int b = blockIdx.x >> 3;
    int op = blockIdx.x & 7;
    int j = threadIdx.x;
    const float* V = ws + V_OFF + b * 512 + op * 64;
    const float* w = wo + (size_t)(op * 64) * 512 + j;
    float acc = 0.f;
#pragma unroll 8
    for (int oi = 0; oi < 64; ++oi) acc += V[oi] * w[(size_t)oi * 512];
    atomicAdd(ws + ROW_OFF + b * 512 + j, acc);
}

// ---- broadcast: out[b,l,:] = row[b,:]  (float4 stores) ----
__global__ __launch_bounds__(256) void k9_out(const float* __restrict__ ws, float* __restrict__ out) {
    const float4* row4 = (const float4*)(ws + ROW_OFF);
    float4* out4 = (float4*)out;
    size_t stride = (size_t)gridDim.x * blockDim.x;
    for (size_t g = (size_t)blockIdx.x * blockDim.x + threadIdx.x; g < 8388608ull; g += stride) {
        int b = (int)(g >> 20);          // 8192 rows * 128 float4/row = 2^20 per batch
        int q = (int)(g & 127);
        out4[g] = row4[b * 128 + q];
    }
}

extern "C" void kernel_launch(void* const* d_in, const int* in_sizes, int n_in,
                              void* d_out, int out_size, void* d_ws, size_t ws_size,
                              hipStream_t stream) {
    const float* x   = (const float*)d_in[0];
    const float* poi = (const float*)d_in[1];
    const float* wq1 = (const float*)d_in[2];
    const float* bq1 = (const float*)d_in[3];
    const float* wq2 = (const float*)d_in[4];
    const float* bq2 = (const float*)d_in[5];
    const float* wk  = (const float*)d_in[6];
    const float* bk  = (const float*)d_in[7];
    const float* wv  = (const float*)d_in[8];
    const float* bv  = (const float*)d_in[9];
    const float* wo  = (const float*)d_in[10];
    const float* bo  = (const float*)d_in[11];
    float* ws  = (float*)d_ws;
    float* out = (float*)d_out;

    k0_init<<<160, 256, 0, stream>>>(ws, bv, bo);
    k1_qraw<<<7, 256, 0, stream>>>(poi, wq1, bq1, ws);
    k2_qf<<<512, 256, 0, stream>>>(wq2, bq2, ws);
    k3_qkvec<<<16, 256, 0, stream>>>(wk, bk, ws);
    k4_scores<<<1024, 256, 0, stream>>>(x, ws);
    k5_softmax<<<64, 256, 0, stream>>>(ws);
    k6_y<<<1024, 512, 0, stream>>>(x, ws);
    k7_v<<<64, 512, 0, stream>>>(wv, ws);
    k8_row<<<64, 512, 0, stream>>>(wo, ws);
    k9_out<<<2048, 256, 0, stream>>>(ws, out);
}